// Round 4
// baseline (11795.294 us; speedup 1.0000x reference)
//
#include <hip/hip_runtime.h>
#include <hip/hip_bf16.h>
#include <math.h>

// Problem dims
#define NL 6
#define DD 768
#define DI 1024
#define NH 8
#define HDIM 96
#define FFD 3072
#define NV 32000
#define NB 8
#define NS 512
#define NP 196

#define INV_SCALE 0.03608439182435161f  // 1/sqrt(768)
#define LN_EPS 1e-5f

// ---------------------------------------------------------------------------
// Embedding + positional encoding: x[b,s,d] = table[tok[b,s]][d] + pe(s,d)
// ---------------------------------------------------------------------------
__global__ __launch_bounds__(256) void embed_kernel(
    const int* __restrict__ tokens, const float* __restrict__ table,
    float* __restrict__ X)
{
    int bs = blockIdx.x;           // 0..B*S-1
    int s = bs & (NS - 1);
    int tok = tokens[bs];
    const float* trow = table + (size_t)tok * DD;
    float* xrow = X + (size_t)bs * DD;
    const float LOG1E4_OVER_D = 9.210340371976184f / 768.0f;
    #pragma unroll
    for (int r = 0; r < 3; ++r) {
        int d = threadIdx.x + r * 256;
        int i2 = d & ~1;
        float freq = __expf(-(float)i2 * LOG1E4_OVER_D); // 10000^{-i2/768}
        float ang = (float)s * freq;
        float pe = (d & 1) ? cosf(ang) : sinf(ang);
        xrow[d] = trow[d] + pe;
    }
}

// ---------------------------------------------------------------------------
// fp32 GEMM: C[M,N] = A[M,K] @ W[K,N] + bias (+ Res) (+ relu)
// BN=128, BM in {64,128}, BK=16, 256 threads (16x16 grid).
// Micro-tile: rows {ty*4, ty*4+64(if BM=128)}, cols {tx*4, tx*4+64} ->
// all LDS reads are float4 at 16B stride => <=2-way bank aliasing (free).
// Per thread per kk: MR*8 FMA vs (MR/4+2) float4 LDS reads -> VALU-bound.
// Requires K%16==0, N%128==0; M may be ragged (guarded).
// ---------------------------------------------------------------------------
template<int BM, int RELU, int ADDRES>
__global__ __launch_bounds__(256) void gemm_mt(
    const float* __restrict__ A, const float* __restrict__ W,
    const float* __restrict__ bias, const float* __restrict__ Res,
    float* __restrict__ C, int M, int N, int K)
{
    constexpr int MR = BM / 16;            // 8 (BM=128) or 4 (BM=64)
    __shared__ float As[16][BM];           // transposed A tile [k][m]
    __shared__ float Bs[16][128];          // B tile [k][n]
    const int tid = threadIdx.x;
    const int tx = tid & 15, ty = tid >> 4;
    const int row0 = blockIdx.y * BM, col0 = blockIdx.x * 128;
    const int am = tid >> 2;               // 0..63 (A tile row)
    const int ak = (tid & 3) * 4;          // k offset 0,4,8,12
    const int bk = tid >> 4;               // 0..15 (B tile k)
    const int bn = (tid & 15) * 4;         // 0..60 (B col offset)
    float acc[MR][8] = {};

    for (int kt = 0; kt < K; kt += 16) {
        #pragma unroll
        for (int r = 0; r < BM / 64; ++r) {
            int m = am + r * 64;
            float4 av = make_float4(0.f, 0.f, 0.f, 0.f);
            if (row0 + m < M)
                av = *reinterpret_cast<const float4*>(
                    A + (size_t)(row0 + m) * K + kt + ak);
            As[ak + 0][m] = av.x; As[ak + 1][m] = av.y;
            As[ak + 2][m] = av.z; As[ak + 3][m] = av.w;
        }
        *reinterpret_cast<float4*>(&Bs[bk][bn]) =
            *reinterpret_cast<const float4*>(W + (size_t)(kt + bk) * N + col0 + bn);
        *reinterpret_cast<float4*>(&Bs[bk][bn + 64]) =
            *reinterpret_cast<const float4*>(W + (size_t)(kt + bk) * N + col0 + bn + 64);
        __syncthreads();
        #pragma unroll
        for (int kk = 0; kk < 16; ++kk) {
            float4 a0 = *reinterpret_cast<const float4*>(&As[kk][ty * 4]);
            float4 a1 = (BM == 128)
                ? *reinterpret_cast<const float4*>(&As[kk][ty * 4 + 64]) : a0;
            float4 b0 = *reinterpret_cast<const float4*>(&Bs[kk][tx * 4]);
            float4 b1 = *reinterpret_cast<const float4*>(&Bs[kk][tx * 4 + 64]);
            float a[8] = {a0.x, a0.y, a0.z, a0.w, a1.x, a1.y, a1.z, a1.w};
            float b[8] = {b0.x, b0.y, b0.z, b0.w, b1.x, b1.y, b1.z, b1.w};
            #pragma unroll
            for (int i = 0; i < MR; ++i)
                #pragma unroll
                for (int j = 0; j < 8; ++j)
                    acc[i][j] += a[i] * b[j];
        }
        __syncthreads();
    }

    #pragma unroll
    for (int i = 0; i < MR; ++i) {
        int r = row0 + ty * 4 + (i & 3) + (i >> 2) * 64;
        if (r >= M) continue;
        #pragma unroll
        for (int ci = 0; ci < 2; ++ci) {
            int c = col0 + tx * 4 + ci * 64;
            float4 v;
            v.x = acc[i][ci * 4 + 0] + bias[c + 0];
            v.y = acc[i][ci * 4 + 1] + bias[c + 1];
            v.z = acc[i][ci * 4 + 2] + bias[c + 2];
            v.w = acc[i][ci * 4 + 3] + bias[c + 3];
            if (ADDRES) {
                float4 rv = *reinterpret_cast<const float4*>(Res + (size_t)r * N + c);
                v.x += rv.x; v.y += rv.y; v.z += rv.z; v.w += rv.w;
            }
            if (RELU) {
                v.x = fmaxf(v.x, 0.f); v.y = fmaxf(v.y, 0.f);
                v.z = fmaxf(v.z, 0.f); v.w = fmaxf(v.w, 0.f);
            }
            *reinterpret_cast<float4*>(C + (size_t)r * N + c) = v;
        }
    }
}

// ---------------------------------------------------------------------------
// Attention scores: Sc[z, i, j] = dot(Q[z,i,:96], K[z,j,:96]) * INV_SCALE
// (+ causal mask).  z = b*H + h.
// ---------------------------------------------------------------------------
__global__ __launch_bounds__(256) void attn_scores_kernel(
    const float* __restrict__ Q, long q_bstride, int q_rstride,
    const float* __restrict__ Kp, long k_bstride, int k_rstride,
    float* __restrict__ Sc, int NK, int causal)
{
    __shared__ float Qs[32][100];
    __shared__ float Ks[32][100];
    int z = blockIdx.z;
    int b = z >> 3, h = z & 7;
    const float* qb = Q + (size_t)b * q_bstride + h * HDIM;
    const float* kb = Kp + (size_t)b * k_bstride + h * HDIM;
    int i0 = blockIdx.y * 32;
    int j0 = blockIdx.x * 32;
    int tid = threadIdx.x;
    for (int u = tid; u < 768; u += 256) {   // 32 rows x 24 float4
        int r = u / 24, c4 = (u % 24) * 4;
        *reinterpret_cast<float4*>(&Qs[r][c4]) =
            *reinterpret_cast<const float4*>(qb + (size_t)(i0 + r) * q_rstride + c4);
        float4 kv = make_float4(0.f, 0.f, 0.f, 0.f);
        if (j0 + r < NK)
            kv = *reinterpret_cast<const float4*>(kb + (size_t)(j0 + r) * k_rstride + c4);
        *reinterpret_cast<float4*>(&Ks[r][c4]) = kv;
    }
    __syncthreads();
    int ti = tid >> 4, tj = tid & 15;
    int ii = ti * 2, jj = tj * 2;
    float acc[2][2] = {};
    #pragma unroll 8
    for (int k = 0; k < HDIM; ++k) {
        float a0 = Qs[ii][k], a1 = Qs[ii + 1][k];
        float b0 = Ks[jj][k], b1 = Ks[jj + 1][k];
        acc[0][0] += a0 * b0; acc[0][1] += a0 * b1;
        acc[1][0] += a1 * b0; acc[1][1] += a1 * b1;
    }
    float* out = Sc + (size_t)z * NS * NK;
    #pragma unroll
    for (int di = 0; di < 2; ++di) {
        int ig = i0 + ii + di;
        #pragma unroll
        for (int dj = 0; dj < 2; ++dj) {
            int jg = j0 + jj + dj;
            if (jg >= NK) continue;
            float v = acc[di][dj] * INV_SCALE;
            if (causal && jg > ig) v = -1e30f;
            out[(size_t)ig * NK + jg] = v;
        }
    }
}

// ---------------------------------------------------------------------------
// Row softmax in place. One 64-lane wave per row; 4 rows per block. NK<=512.
// ---------------------------------------------------------------------------
__global__ __launch_bounds__(256) void softmax_kernel(float* __restrict__ Sc, int NK)
{
    int row = blockIdx.x * 4 + (threadIdx.x >> 6);
    int lane = threadIdx.x & 63;
    float* p = Sc + (size_t)row * NK;
    float e[8];
    int n = 0;
    float m = -1e30f;
    for (int j = lane; j < NK; j += 64) { float v = p[j]; e[n++] = v; m = fmaxf(m, v); }
    #pragma unroll
    for (int o = 32; o; o >>= 1) m = fmaxf(m, __shfl_xor(m, o));
    float s = 0.f;
    for (int i = 0; i < n; ++i) { e[i] = __expf(e[i] - m); s += e[i]; }
    #pragma unroll
    for (int o = 32; o; o >>= 1) s += __shfl_xor(s, o);
    float inv = 1.0f / s;
    n = 0;
    for (int j = lane; j < NK; j += 64) p[j] = e[n++] * inv;
}

// ---------------------------------------------------------------------------
// PV: O[z, i, hd] = sum_j Att[z,i,j] * V[z,j,hd]
// Output written in the "no-transpose reshape" layout:
//   O + b*S*D + h*S*HD + i*HD + hd
// ---------------------------------------------------------------------------
__global__ __launch_bounds__(256) void attn_pv_kernel(
    const float* __restrict__ Att, const float* __restrict__ Vp,
    long v_bstride, int v_rstride, float* __restrict__ O, int NK)
{
    __shared__ float As[32][33];
    __shared__ float Vs[32][100];
    int z = blockIdx.z, b = z >> 3, h = z & 7;
    const float* vb = Vp + (size_t)b * v_bstride + h * HDIM;
    const float* ab = Att + (size_t)z * NS * NK;
    int i0 = blockIdx.y * 32;
    int tid = threadIdx.x;
    int i = tid >> 3;            // 0..31
    int c0 = (tid & 7) * 12;     // 0..84
    float acc[12] = {};
    for (int jt = 0; jt < NK; jt += 32) {
        {
            int r = tid >> 3, c = (tid & 7) * 4;
            #pragma unroll
            for (int u = 0; u < 4; ++u) {
                int jg = jt + c + u;
                As[r][c + u] = (jg < NK) ? ab[(size_t)(i0 + r) * NK + jg] : 0.f;
            }
        }
        for (int u = tid; u < 768; u += 256) {
            int r = u / 24, c4 = (u % 24) * 4;
            float4 vv = make_float4(0.f, 0.f, 0.f, 0.f);
            if (jt + r < NK)
                vv = *reinterpret_cast<const float4*>(vb + (size_t)(jt + r) * v_rstride + c4);
            *reinterpret_cast<float4*>(&Vs[r][c4]) = vv;
        }
        __syncthreads();
        #pragma unroll 8
        for (int jj = 0; jj < 32; ++jj) {
            float a = As[i][jj];
            #pragma unroll
            for (int c = 0; c < 12; ++c) acc[c] += a * Vs[jj][c0 + c];
        }
        __syncthreads();
    }
    float* ob = O + (size_t)b * (NS * DD) + (size_t)h * (NS * HDIM)
                  + (size_t)(i0 + i) * HDIM + c0;
    #pragma unroll
    for (int c = 0; c < 12; ++c) ob[c] = acc[c];
}

// ---------------------------------------------------------------------------
// LayerNorm: X[row,:] = g * (Y-mu) * rsqrt(var+eps) + b    (row len 768)
// ---------------------------------------------------------------------------
__global__ __launch_bounds__(256) void layernorm_kernel(
    const float* __restrict__ Y, const float* __restrict__ g,
    const float* __restrict__ bb, float* __restrict__ X)
{
    __shared__ float sbuf[4];
    int row = blockIdx.x;
    const float* y = Y + (size_t)row * DD;
    int tid = threadIdx.x;
    float v0 = y[tid], v1 = y[tid + 256], v2 = y[tid + 512];
    float s = v0 + v1 + v2;
    #pragma unroll
    for (int o = 32; o; o >>= 1) s += __shfl_xor(s, o);
    if ((tid & 63) == 0) sbuf[tid >> 6] = s;
    __syncthreads();
    float mu = (sbuf[0] + sbuf[1] + sbuf[2] + sbuf[3]) * (1.0f / 768.0f);
    __syncthreads();
    float d0 = v0 - mu, d1 = v1 - mu, d2 = v2 - mu;
    s = d0 * d0 + d1 * d1 + d2 * d2;
    #pragma unroll
    for (int o = 32; o; o >>= 1) s += __shfl_xor(s, o);
    if ((tid & 63) == 0) sbuf[tid >> 6] = s;
    __syncthreads();
    float var = (sbuf[0] + sbuf[1] + sbuf[2] + sbuf[3]) * (1.0f / 768.0f);
    float rinv = rsqrtf(var + LN_EPS);
    float* x = X + (size_t)row * DD;
    x[tid]       = g[tid]       * d0 * rinv + bb[tid];
    x[tid + 256] = g[tid + 256] * d1 * rinv + bb[tid + 256];
    x[tid + 512] = g[tid + 512] * d2 * rinv + bb[tid + 512];
}

// ---------------------------------------------------------------------------
// Host-side orchestration
// ---------------------------------------------------------------------------
extern "C" void kernel_launch(void* const* d_in, const int* in_sizes, int n_in,
                              void* d_out, int out_size, void* d_ws, size_t ws_size,
                              hipStream_t stream)
{
    const int*   tokens    = (const int*)  d_in[0];
    const float* img_emb   = (const float*)d_in[1];
    const float* emb_table = (const float*)d_in[2];
    const float* qkv_W     = (const float*)d_in[3];
    const float* qkv_b     = (const float*)d_in[4];
    const float* sa_proj_W = (const float*)d_in[5];
    const float* sa_proj_b = (const float*)d_in[6];
    const float* sa_ln_g   = (const float*)d_in[7];
    const float* sa_ln_b   = (const float*)d_in[8];
    const float* mq_W      = (const float*)d_in[9];
    const float* mq_b      = (const float*)d_in[10];
    const float* mk_W      = (const float*)d_in[11];
    const float* mk_b      = (const float*)d_in[12];
    const float* mv_W      = (const float*)d_in[13];
    const float* mv_b      = (const float*)d_in[14];
    const float* ca_proj_W = (const float*)d_in[15];
    const float* ca_proj_b = (const float*)d_in[16];
    const float* ca_ln_g   = (const float*)d_in[17];
    const float* ca_ln_b   = (const float*)d_in[18];
    const float* ff1_W     = (const float*)d_in[19];
    const float* ff1_b     = (const float*)d_in[20];
    const float* ff2_W     = (const float*)d_in[21];
    const float* ff2_b     = (const float*)d_in[22];
    const float* proj_W    = (const float*)d_in[23];
    const float* proj_b    = (const float*)d_in[24];

    float* ws = (float*)d_ws;
    const size_t XSZ  = (size_t)NB * NS * DD;       // 3,145,728
    const size_t QKVS = (size_t)NB * NS * 3 * DD;   // 9,437,184
    const size_t BIGS = (size_t)NB * NH * NS * NS;  // 16,777,216
    const size_t CKS  = (size_t)NB * NP * DD;       // 1,204,224
    float* x    = ws;
    float* y    = x + XSZ;
    float* qkv  = y + XSZ;          // also reused as cross-attn Q
    float* big  = qkv + QKVS;       // scores / ff1 activations
    float* o    = big + BIGS;
    float* ck   = o + XSZ;
    float* cv   = ck + CKS;
    // total = 38,169,632 floats = ~153 MB (must fit ws_size)

    const int MROWS = NB * NS;          // 4096
    const int MIMG  = NB * NP;          // 1568

    embed_kernel<<<MROWS, 256, 0, stream>>>(tokens, emb_table, x);

    for (int l = 0; l < NL; ++l) {
        // ======== masked self-attention ========
        gemm_mt<128,0,0><<<dim3(3 * DD / 128, MROWS / 128), 256, 0, stream>>>(
            x, qkv_W + (size_t)l * DD * 3 * DD, qkv_b + (size_t)l * 3 * DD,
            nullptr, qkv, MROWS, 3 * DD, DD);
        attn_scores_kernel<<<dim3(NS / 32, NS / 32, NB * NH), 256, 0, stream>>>(
            qkv,          (long)NS * 3 * DD, 3 * DD,
            qkv + DD,     (long)NS * 3 * DD, 3 * DD,
            big, NS, 1);
        softmax_kernel<<<NB * NH * NS / 4, 256, 0, stream>>>(big, NS);
        attn_pv_kernel<<<dim3(1, NS / 32, NB * NH), 256, 0, stream>>>(
            big, qkv + 2 * DD, (long)NS * 3 * DD, 3 * DD, o, NS);
        gemm_mt<64,0,1><<<dim3(DD / 128, MROWS / 64), 256, 0, stream>>>(
            o, sa_proj_W + (size_t)l * DD * DD, sa_proj_b + (size_t)l * DD,
            x, y, MROWS, DD, DD);
        layernorm_kernel<<<MROWS, 256, 0, stream>>>(
            y, sa_ln_g + (size_t)l * DD, sa_ln_b + (size_t)l * DD, x);

        // ======== cross-attention ========
        gemm_mt<64,0,0><<<dim3(DD / 128, MROWS / 64), 256, 0, stream>>>(
            x, mq_W + (size_t)l * DD * DD, mq_b + (size_t)l * DD,
            nullptr, qkv, MROWS, DD, DD);              // qkv buf = cross Q
        gemm_mt<64,0,0><<<dim3(DD / 128, (MIMG + 63) / 64), 256, 0, stream>>>(
            img_emb, mk_W + (size_t)l * DI * DD, mk_b + (size_t)l * DD,
            nullptr, ck, MIMG, DD, DI);
        gemm_mt<64,0,0><<<dim3(DD / 128, (MIMG + 63) / 64), 256, 0, stream>>>(
            img_emb, mv_W + (size_t)l * DI * DD, mv_b + (size_t)l * DD,
            nullptr, cv, MIMG, DD, DI);
        attn_scores_kernel<<<dim3((NP + 31) / 32, NS / 32, NB * NH), 256, 0, stream>>>(
            qkv, (long)NS * DD, DD,
            ck,  (long)NP * DD, DD,
            big, NP, 0);
        softmax_kernel<<<NB * NH * NS / 4, 256, 0, stream>>>(big, NP);
        attn_pv_kernel<<<dim3(1, NS / 32, NB * NH), 256, 0, stream>>>(
            big, cv, (long)NP * DD, DD, o, NP);
        gemm_mt<64,0,1><<<dim3(DD / 128, MROWS / 64), 256, 0, stream>>>(
            o, ca_proj_W + (size_t)l * DD * DD, ca_proj_b + (size_t)l * DD,
            x, y, MROWS, DD, DD);
        layernorm_kernel<<<MROWS, 256, 0, stream>>>(
            y, ca_ln_g + (size_t)l * DD, ca_ln_b + (size_t)l * DD, x);

        // ======== feed-forward (no residual) ========
        gemm_mt<128,1,0><<<dim3(FFD / 128, MROWS / 128), 256, 0, stream>>>(
            x, ff1_W + (size_t)l * DD * FFD, ff1_b + (size_t)l * FFD,
            nullptr, big, MROWS, FFD, DD);
        gemm_mt<64,0,0><<<dim3(DD / 128, MROWS / 64), 256, 0, stream>>>(
            big, ff2_W + (size_t)l * FFD * DD, ff2_b + (size_t)l * DD,
            nullptr, x, MROWS, DD, FFD);
    }

    // ======== final vocab projection ========
    gemm_mt<128,0,0><<<dim3(NV / 128, MROWS / 128), 256, 0, stream>>>(
        x, proj_W, proj_b, nullptr, (float*)d_out, MROWS, NV, DD);
}